// Round 1
// baseline (563.501 us; speedup 1.0000x reference)
//
#include <hip/hip_runtime.h>
#include <hip/hip_bf16.h>
#include <math.h>

// Problem constants: N=100000 entities, D=256, E=1.6M edges (read N/E from in_sizes).
#define D 256

typedef short s16x8 __attribute__((ext_vector_type(8)));
typedef float f32x4 __attribute__((ext_vector_type(4)));

__device__ __forceinline__ unsigned short f2bf(float f) {
    unsigned int u = __builtin_bit_cast(unsigned int, f);
    unsigned int r = (u + 0x7fffu + ((u >> 16) & 1u)) >> 16;  // round-nearest-even
    return (unsigned short)r;
}
__device__ __forceinline__ float bf2f(unsigned short s) {
    unsigned int u = ((unsigned int)s) << 16;
    return __builtin_bit_cast(float, u);
}

// Pre-swizzle W (fp32 [D][D], row-major, h = x @ W uses W[k][n]) into MFMA
// B-fragment order for 16x16x32 bf16:
//   Wsw[((kt*16 + nt)*64 + lane)*8 + j] = bf16(W[kt*32 + (lane>>4)*8 + j][nt*16 + (lane&15)])
// so a wave's b-frag load is 16 B/lane, 1 KB contiguous.
__global__ void swizzle_w(const float* __restrict__ W1, const float* __restrict__ Wr,
                          unsigned short* __restrict__ W1sw, unsigned short* __restrict__ Wrsw) {
    int idx = blockIdx.x * blockDim.x + threadIdx.x;  // 0 .. 2*65536-1
    int m = idx >> 16;
    int t = idx & 65535;
    const float* src = m ? Wr : W1;
    unsigned short* dst = m ? Wrsw : W1sw;
    int j = t & 7, lane = (t >> 3) & 63, nt = (t >> 9) & 15, kt = t >> 13;
    int k = kt * 32 + (lane >> 4) * 8 + j;
    int n = nt * 16 + (lane & 15);
    dst[t] = f2bf(src[k * D + n]);
}

// edge_rows is sorted ascending: row_ptr[r] = lower_bound(rows, r); r in [0, N].
__global__ void build_row_ptr(const int* __restrict__ rows, int* __restrict__ rp, int N, int E) {
    int r = blockIdx.x * blockDim.x + threadIdx.x;
    if (r > N) return;
    int lo = 0, hi = E;
    while (lo < hi) {
        int mid = (lo + hi) >> 1;
        if (rows[mid] < r) lo = mid + 1; else hi = mid;
    }
    rp[r] = lo;
}

// h[N][D] (bf16) = X[N][D] (fp32) @ W (pre-swizzled bf16).
// Block = 256 threads = 4 waves; wave computes 16 rows x 256 cols via 16 MFMA tiles.
__global__ __launch_bounds__(256) void gemm1(const float* __restrict__ X,
                                             const unsigned short* __restrict__ Wsw,
                                             unsigned short* __restrict__ h, int N) {
    int lane = threadIdx.x & 63;
    int wave = threadIdx.x >> 6;
    int quad = lane >> 4;
    int m_base = blockIdx.x * 64 + wave * 16;
    int rowA = m_base + (lane & 15);
    if (rowA >= N) rowA = N - 1;  // clamp; stores are guarded
    const float* ap0 = X + (size_t)rowA * D + quad * 8;

    f32x4 acc[16];
#pragma unroll
    for (int i = 0; i < 16; i++) acc[i] = (f32x4){0.f, 0.f, 0.f, 0.f};

#pragma unroll
    for (int kt = 0; kt < 8; kt++) {
        float4 a0 = *(const float4*)(ap0 + kt * 32);
        float4 a1 = *(const float4*)(ap0 + kt * 32 + 4);
        s16x8 afrag;
        afrag[0] = (short)f2bf(a0.x); afrag[1] = (short)f2bf(a0.y);
        afrag[2] = (short)f2bf(a0.z); afrag[3] = (short)f2bf(a0.w);
        afrag[4] = (short)f2bf(a1.x); afrag[5] = (short)f2bf(a1.y);
        afrag[6] = (short)f2bf(a1.z); afrag[7] = (short)f2bf(a1.w);
        const s16x8* bp = (const s16x8*)(Wsw + ((size_t)(kt * 16) * 64 + lane) * 8);
#pragma unroll
        for (int nt = 0; nt < 16; nt++) {
            s16x8 bfrag = bp[nt * 64];
            acc[nt] = __builtin_amdgcn_mfma_f32_16x16x32_bf16(afrag, bfrag, acc[nt], 0, 0, 0);
        }
    }
    // C/D layout: col = lane&15, row = quad*4 + reg
#pragma unroll
    for (int nt = 0; nt < 16; nt++) {
        int col = nt * 16 + (lane & 15);
#pragma unroll
        for (int r = 0; r < 4; r++) {
            int row = m_base + quad * 4 + r;
            if (row < N) h[(size_t)row * D + col] = f2bf(acc[nt][r]);
        }
    }
}

// agg[r] = relu(sum_{e in segment r} vals[e] * h[cols[e]]), bf16 in/out.
// One block (128 threads) per row; thread t handles cols (2t, 2t+1) as packed uint.
__global__ void scatter_agg(const unsigned int* __restrict__ h32,
                            const int* __restrict__ rp, const int* __restrict__ cols,
                            const float* __restrict__ vals,
                            unsigned int* __restrict__ agg32, int N) {
    int r = blockIdx.x;
    int t = threadIdx.x;  // 0..127
    int start = rp[r], end = rp[r + 1];
    float ax = 0.f, ay = 0.f;
    for (int e = start; e < end; e++) {
        int c = cols[e];
        float v = vals[e];
        unsigned int u = h32[(size_t)c * 128 + t];
        ax += v * bf2f((unsigned short)(u & 0xffffu));
        ay += v * bf2f((unsigned short)(u >> 16));
    }
    ax = fmaxf(ax, 0.f);
    ay = fmaxf(ay, 0.f);
    agg32[(size_t)r * 128 + t] = (unsigned int)f2bf(ax) | ((unsigned int)f2bf(ay) << 16);
}

// pre = X[perm[row]] @ Wr ; gate = sigmoid(pre + br); out = gate*agg + (1-gate)*left.
__global__ __launch_bounds__(256) void gemm2(const float* __restrict__ X,
                                             const int* __restrict__ perm,
                                             const unsigned short* __restrict__ Wsw,
                                             const float* __restrict__ br,
                                             const unsigned short* __restrict__ agg,
                                             float* __restrict__ out, int N) {
    int lane = threadIdx.x & 63;
    int wave = threadIdx.x >> 6;
    int quad = lane >> 4;
    int m_base = blockIdx.x * 64 + wave * 16;
    int rowA = m_base + (lane & 15);
    if (rowA >= N) rowA = N - 1;
    int srcA = perm[rowA];
    const float* ap0 = X + (size_t)srcA * D + quad * 8;

    f32x4 acc[16];
#pragma unroll
    for (int i = 0; i < 16; i++) acc[i] = (f32x4){0.f, 0.f, 0.f, 0.f};

#pragma unroll
    for (int kt = 0; kt < 8; kt++) {
        float4 a0 = *(const float4*)(ap0 + kt * 32);
        float4 a1 = *(const float4*)(ap0 + kt * 32 + 4);
        s16x8 afrag;
        afrag[0] = (short)f2bf(a0.x); afrag[1] = (short)f2bf(a0.y);
        afrag[2] = (short)f2bf(a0.z); afrag[3] = (short)f2bf(a0.w);
        afrag[4] = (short)f2bf(a1.x); afrag[5] = (short)f2bf(a1.y);
        afrag[6] = (short)f2bf(a1.z); afrag[7] = (short)f2bf(a1.w);
        const s16x8* bp = (const s16x8*)(Wsw + ((size_t)(kt * 16) * 64 + lane) * 8);
#pragma unroll
        for (int nt = 0; nt < 16; nt++) {
            s16x8 bfrag = bp[nt * 64];
            acc[nt] = __builtin_amdgcn_mfma_f32_16x16x32_bf16(afrag, bfrag, acc[nt], 0, 0, 0);
        }
    }

    // epilogue: per C element (row = m_base+quad*4+r, col = nt*16+(lane&15))
    int prow[4];
#pragma unroll
    for (int r = 0; r < 4; r++) {
        int row = m_base + quad * 4 + r;
        prow[r] = perm[row < N ? row : N - 1];
    }
#pragma unroll
    for (int nt = 0; nt < 16; nt++) {
        int col = nt * 16 + (lane & 15);
        float b = br[col];
#pragma unroll
        for (int r = 0; r < 4; r++) {
            int row = m_base + quad * 4 + r;
            if (row < N) {
                float pre = acc[nt][r] + b;
                float gate = 1.f / (1.f + __expf(-pre));
                float gcn = bf2f(agg[(size_t)row * D + col]);
                float left = X[(size_t)prow[r] * D + col];
                out[(size_t)row * D + col] = gate * gcn + (1.f - gate) * left;
            }
        }
    }
}

extern "C" void kernel_launch(void* const* d_in, const int* in_sizes, int n_in,
                              void* d_out, int out_size, void* d_ws, size_t ws_size,
                              hipStream_t stream) {
    const float* right = (const float*)d_in[0];  // [N,D] fp32
    const float* W1    = (const float*)d_in[1];  // [D,D]
    const float* Wr    = (const float*)d_in[2];  // [D,D]
    const float* br    = (const float*)d_in[3];  // [D]
    const float* evals = (const float*)d_in[4];  // [E]
    const int*   erows = (const int*)d_in[5];    // [E] sorted
    const int*   ecols = (const int*)d_in[6];    // [E]
    const int*   perm  = (const int*)d_in[7];    // [N]
    int N = in_sizes[7];
    int E = in_sizes[4];
    float* out = (float*)d_out;

    // Workspace layout (~103 MB total):
    //   [0]            W1sw  : D*D bf16 = 128 KB
    //   [+128K]        Wrsw  : 128 KB
    //   [+256K]        rp    : (N+1) int
    //   [align 256]    h     : N*D bf16 (51.2 MB)
    //   [...]          agg   : N*D bf16 (51.2 MB)
    char* ws = (char*)d_ws;
    unsigned short* W1sw = (unsigned short*)ws;
    unsigned short* Wrsw = W1sw + D * D;
    int* rp = (int*)(ws + (size_t)2 * D * D * 2);
    size_t off = (size_t)2 * D * D * 2 + 4 * (size_t)(N + 1);
    off = (off + 255) & ~(size_t)255;
    unsigned short* h = (unsigned short*)(ws + off);
    unsigned short* agg = h + (size_t)N * D;

    swizzle_w<<<512, 256, 0, stream>>>(W1, Wr, W1sw, Wrsw);
    build_row_ptr<<<(N + 256) / 256, 256, 0, stream>>>(erows, rp, N, E);
    int gblocks = (N + 63) / 64;
    gemm1<<<gblocks, 256, 0, stream>>>(right, W1sw, h, N);
    scatter_agg<<<N, 128, 0, stream>>>((const unsigned int*)h, rp, ecols, evals,
                                       (unsigned int*)agg, N);
    gemm2<<<gblocks, 256, 0, stream>>>(right, perm, Wrsw, br, agg, out, N);
}

// Round 2
// 428.941 us; speedup vs baseline: 1.3137x; 1.3137x over previous
//
#include <hip/hip_runtime.h>
#include <hip/hip_bf16.h>
#include <math.h>

#define D 256

typedef short s16x8 __attribute__((ext_vector_type(8)));
typedef float f32x4 __attribute__((ext_vector_type(4)));

__device__ __forceinline__ unsigned short f2bf(float f) {
    unsigned int u = __builtin_bit_cast(unsigned int, f);
    unsigned int r = (u + 0x7fffu + ((u >> 16) & 1u)) >> 16;  // RNE
    return (unsigned short)r;
}
__device__ __forceinline__ float bf2f(unsigned short s) {
    unsigned int u = ((unsigned int)s) << 16;
    return __builtin_bit_cast(float, u);
}

// Wsw[((kt*16 + nt)*64 + lane)*8 + j] = bf16(W[kt*32 + (lane>>4)*8 + j][nt*16 + (lane&15)])
__global__ void swizzle_w(const float* __restrict__ W1, const float* __restrict__ Wr,
                          unsigned short* __restrict__ W1sw, unsigned short* __restrict__ Wrsw) {
    int idx = blockIdx.x * blockDim.x + threadIdx.x;  // 0 .. 2*65536-1
    int m = idx >> 16;
    int t = idx & 65535;
    const float* src = m ? Wr : W1;
    unsigned short* dst = m ? Wrsw : W1sw;
    int j = t & 7, lane = (t >> 3) & 63, nt = (t >> 9) & 15, kt = t >> 13;
    int k = kt * 32 + (lane >> 4) * 8 + j;
    int n = nt * 16 + (lane & 15);
    dst[t] = f2bf(src[k * D + n]);
}

__global__ void build_row_ptr(const int* __restrict__ rows, int* __restrict__ rp, int N, int E) {
    int r = blockIdx.x * blockDim.x + threadIdx.x;
    if (r > N) return;
    int lo = 0, hi = E;
    while (lo < hi) {
        int mid = (lo + hi) >> 1;
        if (rows[mid] < r) lo = mid + 1; else hi = mid;
    }
    rp[r] = lo;
}

// ---------------- GEMM: B persistent in registers, A staged in LDS ----------------
// Block = 512 thr = 8 waves. Wave w owns cols [w*32, w*32+32) (nt = 2w, 2w+1).
// B slice (16 b-frags = 64 VGPRs) loaded once; grid-stride over 32-row tiles.
// LDS A layout = frag order: lA[((mt*8+kt)*64 + lane)*8 + j], mt in {0,1}.

__device__ __forceinline__ void stage_a_frag(const float* __restrict__ Xrow, int k0,
                                             unsigned short* __restrict__ lA, int fgi) {
    float4 f0 = *(const float4*)(Xrow + k0);
    float4 f1 = *(const float4*)(Xrow + k0 + 4);
    s16x8 sf;
    sf[0] = (short)f2bf(f0.x); sf[1] = (short)f2bf(f0.y);
    sf[2] = (short)f2bf(f0.z); sf[3] = (short)f2bf(f0.w);
    sf[4] = (short)f2bf(f1.x); sf[5] = (short)f2bf(f1.y);
    sf[6] = (short)f2bf(f1.z); sf[7] = (short)f2bf(f1.w);
    *(s16x8*)(lA + (size_t)fgi * 8) = sf;
}

__global__ __launch_bounds__(512) void gemm1_b(const float* __restrict__ X,
                                               const unsigned short* __restrict__ Wsw,
                                               unsigned short* __restrict__ h,
                                               int N, int numTiles) {
    __shared__ unsigned short lA[2 * 8 * 64 * 8];  // 16 KB
    int t = threadIdx.x;
    int lane = t & 63;
    int wave = t >> 6;
    int quad = lane >> 4;

    s16x8 bfr[2][8];
#pragma unroll
    for (int ntl = 0; ntl < 2; ntl++) {
        int nt = wave * 2 + ntl;
#pragma unroll
        for (int kt = 0; kt < 8; kt++)
            bfr[ntl][kt] = *(const s16x8*)(Wsw + ((size_t)((kt * 16 + nt) * 64 + lane)) * 8);
    }

    for (int tile = blockIdx.x; tile < numTiles; tile += gridDim.x) {
        // stage: 1024 frags, 512 threads -> 2 each
#pragma unroll
        for (int q = 0; q < 2; q++) {
            int fgi = q * 512 + t;
            int mt = fgi >> 9, kt = (fgi >> 6) & 7, ll = fgi & 63;
            int rl = ll & 15, qd = ll >> 4;
            int grow = tile * 32 + mt * 16 + rl;
            if (grow >= N) grow = N - 1;
            stage_a_frag(X + (size_t)grow * D, kt * 32 + qd * 8, lA, fgi);
        }
        __syncthreads();

        f32x4 acc[2][2];
#pragma unroll
        for (int mt = 0; mt < 2; mt++)
#pragma unroll
            for (int ntl = 0; ntl < 2; ntl++) acc[mt][ntl] = (f32x4){0.f, 0.f, 0.f, 0.f};

#pragma unroll
        for (int mt = 0; mt < 2; mt++)
#pragma unroll
            for (int kt = 0; kt < 8; kt++) {
                s16x8 a = *(const s16x8*)(lA + (size_t)(((mt * 8 + kt) * 64 + lane)) * 8);
                acc[mt][0] = __builtin_amdgcn_mfma_f32_16x16x32_bf16(a, bfr[0][kt], acc[mt][0], 0, 0, 0);
                acc[mt][1] = __builtin_amdgcn_mfma_f32_16x16x32_bf16(a, bfr[1][kt], acc[mt][1], 0, 0, 0);
            }
        __syncthreads();

#pragma unroll
        for (int mt = 0; mt < 2; mt++)
#pragma unroll
            for (int ntl = 0; ntl < 2; ntl++) {
                int col = (wave * 2 + ntl) * 16 + (lane & 15);
#pragma unroll
                for (int r = 0; r < 4; r++) {
                    int grow = tile * 32 + mt * 16 + quad * 4 + r;
                    if (grow < N) h[(size_t)grow * D + col] = f2bf(acc[mt][ntl][r]);
                }
            }
    }
}

__global__ __launch_bounds__(512) void gemm2_b(const float* __restrict__ X,
                                               const int* __restrict__ perm,
                                               const unsigned short* __restrict__ Wsw,
                                               const float* __restrict__ br,
                                               const unsigned short* __restrict__ agg,
                                               float* __restrict__ out,
                                               int N, int numTiles) {
    __shared__ unsigned short lA[2 * 8 * 64 * 8];  // 16 KB
    int t = threadIdx.x;
    int lane = t & 63;
    int wave = t >> 6;
    int quad = lane >> 4;

    s16x8 bfr[2][8];
#pragma unroll
    for (int ntl = 0; ntl < 2; ntl++) {
        int nt = wave * 2 + ntl;
#pragma unroll
        for (int kt = 0; kt < 8; kt++)
            bfr[ntl][kt] = *(const s16x8*)(Wsw + ((size_t)((kt * 16 + nt) * 64 + lane)) * 8);
    }

    for (int tile = blockIdx.x; tile < numTiles; tile += gridDim.x) {
#pragma unroll
        for (int q = 0; q < 2; q++) {
            int fgi = q * 512 + t;
            int mt = fgi >> 9, kt = (fgi >> 6) & 7, ll = fgi & 63;
            int rl = ll & 15, qd = ll >> 4;
            int grow = tile * 32 + mt * 16 + rl;
            if (grow >= N) grow = N - 1;
            int pr = perm[grow];
            stage_a_frag(X + (size_t)pr * D, kt * 32 + qd * 8, lA, fgi);
        }
        __syncthreads();

        f32x4 acc[2][2];
#pragma unroll
        for (int mt = 0; mt < 2; mt++)
#pragma unroll
            for (int ntl = 0; ntl < 2; ntl++) acc[mt][ntl] = (f32x4){0.f, 0.f, 0.f, 0.f};

#pragma unroll
        for (int mt = 0; mt < 2; mt++)
#pragma unroll
            for (int kt = 0; kt < 8; kt++) {
                s16x8 a = *(const s16x8*)(lA + (size_t)(((mt * 8 + kt) * 64 + lane)) * 8);
                acc[mt][0] = __builtin_amdgcn_mfma_f32_16x16x32_bf16(a, bfr[0][kt], acc[mt][0], 0, 0, 0);
                acc[mt][1] = __builtin_amdgcn_mfma_f32_16x16x32_bf16(a, bfr[1][kt], acc[mt][1], 0, 0, 0);
            }
        __syncthreads();

#pragma unroll
        for (int mt = 0; mt < 2; mt++) {
            int prow[4];
#pragma unroll
            for (int r = 0; r < 4; r++) {
                int grow = tile * 32 + mt * 16 + quad * 4 + r;
                prow[r] = perm[grow < N ? grow : N - 1];
            }
#pragma unroll
            for (int ntl = 0; ntl < 2; ntl++) {
                int col = (wave * 2 + ntl) * 16 + (lane & 15);
                float b = br[col];
#pragma unroll
                for (int r = 0; r < 4; r++) {
                    int grow = tile * 32 + mt * 16 + quad * 4 + r;
                    if (grow < N) {
                        float pre = acc[mt][ntl][r] + b;
                        float gate = 1.f / (1.f + __expf(-pre));
                        float gcn = bf2f(agg[(size_t)grow * D + col]);
                        float left = X[(size_t)prow[r] * D + col];
                        out[(size_t)grow * D + col] = gate * gcn + (1.f - gate) * left;
                    }
                }
            }
        }
    }
}

// ---------------- Scatter: wave-per-row, readlane broadcast, 8-deep gather pipeline ----
__device__ __forceinline__ void acc4(float4& a, uint2 u, float v) {
    float x0 = __builtin_bit_cast(float, u.x << 16);
    float x1 = __builtin_bit_cast(float, u.x & 0xffff0000u);
    float x2 = __builtin_bit_cast(float, u.y << 16);
    float x3 = __builtin_bit_cast(float, u.y & 0xffff0000u);
    a.x += v * x0; a.y += v * x1; a.z += v * x2; a.w += v * x3;
}

__global__ __launch_bounds__(256) void scatter2(const uint2* __restrict__ hp,
                                                const int* __restrict__ rp,
                                                const int* __restrict__ cols,
                                                const float* __restrict__ vals,
                                                uint2* __restrict__ aggp,
                                                int N, int E) {
    int lane = threadIdx.x & 63;
    int wave = threadIdx.x >> 6;
    int row = blockIdx.x * 4 + wave;
    if (row >= N) return;
    int start = rp[row], end = rp[row + 1];

    float4 a = {0.f, 0.f, 0.f, 0.f};
    for (int base = start; base < end; base += 64) {
        int ii = base + lane;
        int iic = ii < E ? ii : E - 1;
        int cl = cols[iic];
        int vbits = __builtin_bit_cast(int, vals[iic]);
        int n = end - base; if (n > 64) n = 64;
        int i = 0;
        for (; i + 8 <= n; i += 8) {
            uint2 u[8]; float vv[8];
#pragma unroll
            for (int k = 0; k < 8; k++) {
                int c = __builtin_amdgcn_readlane(cl, i + k);
                vv[k] = __builtin_bit_cast(float, __builtin_amdgcn_readlane(vbits, i + k));
                u[k] = hp[(size_t)c * 64 + lane];
            }
#pragma unroll
            for (int k = 0; k < 8; k++) acc4(a, u[k], vv[k]);
        }
        for (; i < n; i++) {
            int c = __builtin_amdgcn_readlane(cl, i);
            float v = __builtin_bit_cast(float, __builtin_amdgcn_readlane(vbits, i));
            uint2 u = hp[(size_t)c * 64 + lane];
            acc4(a, u, v);
        }
    }
    a.x = fmaxf(a.x, 0.f); a.y = fmaxf(a.y, 0.f);
    a.z = fmaxf(a.z, 0.f); a.w = fmaxf(a.w, 0.f);
    uint2 o;
    o.x = (unsigned int)f2bf(a.x) | ((unsigned int)f2bf(a.y) << 16);
    o.y = (unsigned int)f2bf(a.z) | ((unsigned int)f2bf(a.w) << 16);
    aggp[(size_t)row * 64 + lane] = o;
}

extern "C" void kernel_launch(void* const* d_in, const int* in_sizes, int n_in,
                              void* d_out, int out_size, void* d_ws, size_t ws_size,
                              hipStream_t stream) {
    const float* right = (const float*)d_in[0];
    const float* W1    = (const float*)d_in[1];
    const float* Wr    = (const float*)d_in[2];
    const float* br    = (const float*)d_in[3];
    const float* evals = (const float*)d_in[4];
    const int*   erows = (const int*)d_in[5];
    const int*   ecols = (const int*)d_in[6];
    const int*   perm  = (const int*)d_in[7];
    int N = in_sizes[7];
    int E = in_sizes[4];
    float* out = (float*)d_out;

    char* ws = (char*)d_ws;
    unsigned short* W1sw = (unsigned short*)ws;
    unsigned short* Wrsw = W1sw + D * D;
    int* rp = (int*)(ws + (size_t)2 * D * D * 2);
    size_t off = (size_t)2 * D * D * 2 + 4 * (size_t)(N + 1);
    off = (off + 255) & ~(size_t)255;
    unsigned short* h = (unsigned short*)(ws + off);
    unsigned short* agg = h + (size_t)N * D;

    int numTiles = (N + 31) / 32;

    swizzle_w<<<512, 256, 0, stream>>>(W1, Wr, W1sw, Wrsw);
    build_row_ptr<<<(N + 256) / 256, 256, 0, stream>>>(erows, rp, N, E);
    gemm1_b<<<512, 512, 0, stream>>>(right, W1sw, h, N, numTiles);
    scatter2<<<(N + 3) / 4, 256, 0, stream>>>((const uint2*)h, rp, ecols, evals,
                                              (uint2*)agg, N, E);
    gemm2_b<<<512, 512, 0, stream>>>(right, perm, Wrsw, br, agg, out, N, numTiles);
}

// Round 3
// 417.146 us; speedup vs baseline: 1.3508x; 1.0283x over previous
//
#include <hip/hip_runtime.h>
#include <hip/hip_bf16.h>
#include <math.h>

#define D 256

typedef short s16x8 __attribute__((ext_vector_type(8)));
typedef float f32x4 __attribute__((ext_vector_type(4)));

__device__ __forceinline__ unsigned short f2bf(float f) {
    unsigned int u = __builtin_bit_cast(unsigned int, f);
    unsigned int r = (u + 0x7fffu + ((u >> 16) & 1u)) >> 16;  // RNE
    return (unsigned short)r;
}
__device__ __forceinline__ float bf2f(unsigned short s) {
    unsigned int u = ((unsigned int)s) << 16;
    return __builtin_bit_cast(float, u);
}

// Wsw[((kt*16 + nt)*64 + lane)*8 + j] = bf16(W[kt*32 + (lane>>4)*8 + j][nt*16 + (lane&15)])
__global__ void swizzle_w(const float* __restrict__ W1, const float* __restrict__ Wr,
                          unsigned short* __restrict__ W1sw, unsigned short* __restrict__ Wrsw) {
    int idx = blockIdx.x * blockDim.x + threadIdx.x;  // 0 .. 2*65536-1
    int m = idx >> 16;
    int t = idx & 65535;
    const float* src = m ? Wr : W1;
    unsigned short* dst = m ? Wrsw : W1sw;
    int j = t & 7, lane = (t >> 3) & 63, nt = (t >> 9) & 15, kt = t >> 13;
    int k = kt * 32 + (lane >> 4) * 8 + j;
    int n = nt * 16 + (lane & 15);
    dst[t] = f2bf(src[k * D + n]);
}

__global__ void build_row_ptr(const int* __restrict__ rows, int* __restrict__ rp, int N, int E) {
    int r = blockIdx.x * blockDim.x + threadIdx.x;
    if (r > N) return;
    int lo = 0, hi = E;
    while (lo < hi) {
        int mid = (lo + hi) >> 1;
        if (rows[mid] < r) lo = mid + 1; else hi = mid;
    }
    rp[r] = lo;
}

// ---------------- GEMM: B persistent in registers, A staged in LDS ----------------
// Block = 512 thr = 8 waves. Wave w owns cols [w*32, w*32+32).
// LDS A layout = frag order: lA[((mt*8+kt)*64 + lane)*8 + j], mt in {0,1};
// element (row_in_tile rt, k): mt=rt>>4, rl=rt&15, kt=k>>5, qd=(k>>3)&3, j=k&7
//   -> lA[((mt*8+kt)*64 + qd*16 + rl)*8 + j]

__device__ __forceinline__ void stage_a_frag(const float* __restrict__ Xrow, int k0,
                                             unsigned short* __restrict__ lA, int fgi) {
    float4 f0 = *(const float4*)(Xrow + k0);
    float4 f1 = *(const float4*)(Xrow + k0 + 4);
    s16x8 sf;
    sf[0] = (short)f2bf(f0.x); sf[1] = (short)f2bf(f0.y);
    sf[2] = (short)f2bf(f0.z); sf[3] = (short)f2bf(f0.w);
    sf[4] = (short)f2bf(f1.x); sf[5] = (short)f2bf(f1.y);
    sf[6] = (short)f2bf(f1.z); sf[7] = (short)f2bf(f1.w);
    *(s16x8*)(lA + (size_t)fgi * 8) = sf;
}

__global__ __launch_bounds__(512) void gemm1_b(const float* __restrict__ X,
                                               const unsigned short* __restrict__ Wsw,
                                               unsigned short* __restrict__ h,
                                               int N, int numTiles) {
    __shared__ unsigned short lA[2 * 8 * 64 * 8];  // 16 KB
    int t = threadIdx.x;
    int lane = t & 63;
    int wave = t >> 6;
    int quad = lane >> 4;

    s16x8 bfr[2][8];
#pragma unroll
    for (int ntl = 0; ntl < 2; ntl++) {
        int nt = wave * 2 + ntl;
#pragma unroll
        for (int kt = 0; kt < 8; kt++)
            bfr[ntl][kt] = *(const s16x8*)(Wsw + ((size_t)((kt * 16 + nt) * 64 + lane)) * 8);
    }

    for (int tile = blockIdx.x; tile < numTiles; tile += gridDim.x) {
#pragma unroll
        for (int q = 0; q < 2; q++) {
            int fgi = q * 512 + t;
            int mt = fgi >> 9, kt = (fgi >> 6) & 7, ll = fgi & 63;
            int rl = ll & 15, qd = ll >> 4;
            int grow = tile * 32 + mt * 16 + rl;
            if (grow >= N) grow = N - 1;
            stage_a_frag(X + (size_t)grow * D, kt * 32 + qd * 8, lA, fgi);
        }
        __syncthreads();

        f32x4 acc[2][2];
#pragma unroll
        for (int mt = 0; mt < 2; mt++)
#pragma unroll
            for (int ntl = 0; ntl < 2; ntl++) acc[mt][ntl] = (f32x4){0.f, 0.f, 0.f, 0.f};

#pragma unroll
        for (int mt = 0; mt < 2; mt++)
#pragma unroll
            for (int kt = 0; kt < 8; kt++) {
                s16x8 a = *(const s16x8*)(lA + (size_t)(((mt * 8 + kt) * 64 + lane)) * 8);
                acc[mt][0] = __builtin_amdgcn_mfma_f32_16x16x32_bf16(a, bfr[0][kt], acc[mt][0], 0, 0, 0);
                acc[mt][1] = __builtin_amdgcn_mfma_f32_16x16x32_bf16(a, bfr[1][kt], acc[mt][1], 0, 0, 0);
            }

#pragma unroll
        for (int mt = 0; mt < 2; mt++)
#pragma unroll
            for (int ntl = 0; ntl < 2; ntl++) {
                int col = (wave * 2 + ntl) * 16 + (lane & 15);
#pragma unroll
                for (int r = 0; r < 4; r++) {
                    int grow = tile * 32 + mt * 16 + quad * 4 + r;
                    if (grow < N) h[(size_t)grow * D + col] = f2bf(acc[mt][ntl][r]);
                }
            }
        __syncthreads();
    }
}

__global__ __launch_bounds__(512) void gemm2_b(const float* __restrict__ X,
                                               const int* __restrict__ perm,
                                               const unsigned short* __restrict__ Wsw,
                                               const float* __restrict__ br,
                                               const unsigned short* __restrict__ agg,
                                               float* __restrict__ out,
                                               int N, int numTiles) {
    __shared__ unsigned short lA[2 * 8 * 64 * 8];  // 16 KB
    int t = threadIdx.x;
    int lane = t & 63;
    int wave = t >> 6;
    int quad = lane >> 4;

    s16x8 bfr[2][8];
#pragma unroll
    for (int ntl = 0; ntl < 2; ntl++) {
        int nt = wave * 2 + ntl;
#pragma unroll
        for (int kt = 0; kt < 8; kt++)
            bfr[ntl][kt] = *(const s16x8*)(Wsw + ((size_t)((kt * 16 + nt) * 64 + lane)) * 8);
    }

    for (int tile = blockIdx.x; tile < numTiles; tile += gridDim.x) {
#pragma unroll
        for (int q = 0; q < 2; q++) {
            int fgi = q * 512 + t;
            int mt = fgi >> 9, kt = (fgi >> 6) & 7, ll = fgi & 63;
            int rl = ll & 15, qd = ll >> 4;
            int grow = tile * 32 + mt * 16 + rl;
            if (grow >= N) grow = N - 1;
            int pr = perm[grow];
            stage_a_frag(X + (size_t)pr * D, kt * 32 + qd * 8, lA, fgi);
        }
        __syncthreads();

        f32x4 acc[2][2];
#pragma unroll
        for (int mt = 0; mt < 2; mt++)
#pragma unroll
            for (int ntl = 0; ntl < 2; ntl++) acc[mt][ntl] = (f32x4){0.f, 0.f, 0.f, 0.f};

#pragma unroll
        for (int mt = 0; mt < 2; mt++)
#pragma unroll
            for (int kt = 0; kt < 8; kt++) {
                s16x8 a = *(const s16x8*)(lA + (size_t)(((mt * 8 + kt) * 64 + lane)) * 8);
                acc[mt][0] = __builtin_amdgcn_mfma_f32_16x16x32_bf16(a, bfr[0][kt], acc[mt][0], 0, 0, 0);
                acc[mt][1] = __builtin_amdgcn_mfma_f32_16x16x32_bf16(a, bfr[1][kt], acc[mt][1], 0, 0, 0);
            }

        // epilogue: left = lA (bf16 of X[perm[row]]) -> no global gather
#pragma unroll
        for (int mt = 0; mt < 2; mt++) {
#pragma unroll
            for (int ntl = 0; ntl < 2; ntl++) {
                int col = (wave * 2 + ntl) * 16 + (lane & 15);
                float b = br[col];
                int kt2 = col >> 5, qd2 = (col >> 3) & 3, j2 = col & 7;
#pragma unroll
                for (int r = 0; r < 4; r++) {
                    int rt = mt * 16 + quad * 4 + r;
                    int grow = tile * 32 + rt;
                    if (grow < N) {
                        float pre = acc[mt][ntl][r] + b;
                        float gate = 1.f / (1.f + __expf(-pre));
                        float gcn = bf2f(agg[(size_t)grow * D + col]);
                        float left = bf2f(lA[(size_t)(((mt * 8 + kt2) * 64 + qd2 * 16 + (rt & 15))) * 8 + j2]);
                        out[(size_t)grow * D + col] = gate * gcn + (1.f - gate) * left;
                    }
                }
            }
        }
        __syncthreads();
    }
}

// ---------------- Scatter: wave-per-row, readlane broadcast, 8-deep gather pipeline ----
__device__ __forceinline__ void acc4(float4& a, uint2 u, float v) {
    float x0 = __builtin_bit_cast(float, u.x << 16);
    float x1 = __builtin_bit_cast(float, u.x & 0xffff0000u);
    float x2 = __builtin_bit_cast(float, u.y << 16);
    float x3 = __builtin_bit_cast(float, u.y & 0xffff0000u);
    a.x += v * x0; a.y += v * x1; a.z += v * x2; a.w += v * x3;
}

__global__ __launch_bounds__(256) void scatter2(const uint2* __restrict__ hp,
                                                const int* __restrict__ rp,
                                                const int* __restrict__ cols,
                                                const float* __restrict__ vals,
                                                uint2* __restrict__ aggp,
                                                int N, int E) {
    int lane = threadIdx.x & 63;
    int wave = threadIdx.x >> 6;
    int row = blockIdx.x * 4 + wave;
    if (row >= N) return;
    int start = rp[row], end = rp[row + 1];

    float4 a = {0.f, 0.f, 0.f, 0.f};
    for (int base = start; base < end; base += 64) {
        int ii = base + lane;
        int iic = ii < E ? ii : E - 1;
        int cl = cols[iic];
        int vbits = __builtin_bit_cast(int, vals[iic]);
        int n = end - base; if (n > 64) n = 64;
        int i = 0;
        for (; i + 8 <= n; i += 8) {
            uint2 u[8]; float vv[8];
#pragma unroll
            for (int k = 0; k < 8; k++) {
                int c = __builtin_amdgcn_readlane(cl, i + k);
                vv[k] = __builtin_bit_cast(float, __builtin_amdgcn_readlane(vbits, i + k));
                u[k] = hp[(size_t)c * 64 + lane];
            }
#pragma unroll
            for (int k = 0; k < 8; k++) acc4(a, u[k], vv[k]);
        }
        for (; i < n; i++) {
            int c = __builtin_amdgcn_readlane(cl, i);
            float v = __builtin_bit_cast(float, __builtin_amdgcn_readlane(vbits, i));
            uint2 u = hp[(size_t)c * 64 + lane];
            acc4(a, u, v);
        }
    }
    a.x = fmaxf(a.x, 0.f); a.y = fmaxf(a.y, 0.f);
    a.z = fmaxf(a.z, 0.f); a.w = fmaxf(a.w, 0.f);
    uint2 o;
    o.x = (unsigned int)f2bf(a.x) | ((unsigned int)f2bf(a.y) << 16);
    o.y = (unsigned int)f2bf(a.z) | ((unsigned int)f2bf(a.w) << 16);
    aggp[(size_t)row * 64 + lane] = o;
}

extern "C" void kernel_launch(void* const* d_in, const int* in_sizes, int n_in,
                              void* d_out, int out_size, void* d_ws, size_t ws_size,
                              hipStream_t stream) {
    const float* right = (const float*)d_in[0];
    const float* W1    = (const float*)d_in[1];
    const float* Wr    = (const float*)d_in[2];
    const float* br    = (const float*)d_in[3];
    const float* evals = (const float*)d_in[4];
    const int*   erows = (const int*)d_in[5];
    const int*   ecols = (const int*)d_in[6];
    const int*   perm  = (const int*)d_in[7];
    int N = in_sizes[7];
    int E = in_sizes[4];
    float* out = (float*)d_out;

    char* ws = (char*)d_ws;
    unsigned short* W1sw = (unsigned short*)ws;
    unsigned short* Wrsw = W1sw + D * D;
    int* rp = (int*)(ws + (size_t)2 * D * D * 2);
    size_t off = (size_t)2 * D * D * 2 + 4 * (size_t)(N + 1);
    off = (off + 255) & ~(size_t)255;
    unsigned short* h = (unsigned short*)(ws + off);
    unsigned short* agg = h + (size_t)N * D;

    int numTiles = (N + 31) / 32;

    swizzle_w<<<512, 256, 0, stream>>>(W1, Wr, W1sw, Wrsw);
    build_row_ptr<<<(N + 256) / 256, 256, 0, stream>>>(erows, rp, N, E);
    gemm1_b<<<numTiles, 512, 0, stream>>>(right, W1sw, h, N, numTiles);
    scatter2<<<(N + 3) / 4, 256, 0, stream>>>((const uint2*)h, rp, ecols, evals,
                                              (uint2*)agg, N, E);
    gemm2_b<<<numTiles, 512, 0, stream>>>(right, perm, Wrsw, br, agg, out, N, numTiles);
}